// Round 1
// baseline (270.209 us; speedup 1.0000x reference)
//
#include <hip/hip_runtime.h>

// DNNF fused pipeline for MI355X (gfx950). R6 = R5 + BM 128->256 (8 waves):
// cache->CU staging traffic drops 1.22 GB -> 0.85 GB (B-side wt stream
// halves: each m-tile row re-reads all of wt, and there are now 32 not 64).
// Same 2-phase double-buffered BK=64 pipeline, same per-wave 4x6 fragment
// inner loop, same XOR k-group swizzle. XCD pinning kept: gridDim.x=32
// m-tiles (%8==0) -> each XCD owns 4 m-tiles (1 MB xb) in its L2.

#define BATCH 8192
#define IDIM 512
#define NFORM 256
#define NLIT 10752
#define WT_ROWS 11136  // NLIT + 256 mu + 128 zero pad; /192 = 58 tiles

#define BM 256
#define BN 192
#define BK 64
#define ABYTES 32768   // 256*64*2
#define BBYTES 24576   // 192*64*2
#define BUFB 57344     // one LDS buffer: A + B
#define SLITP 196      // slit row stride (floats)

typedef __bf16 bf16x8 __attribute__((ext_vector_type(8)));
typedef float f32x4 __attribute__((ext_vector_type(4)));
typedef unsigned short u16;
typedef unsigned int u32;

__device__ __forceinline__ u16 f2bf(float f) {
  u32 u = __float_as_uint(f);
  u = (u + 0x7fffu + ((u >> 16) & 1u)) >> 16;  // RNE
  return (u16)u;
}

__device__ __forceinline__ float fast_tanh(float x) {
  float e = __expf(2.0f * x);
  return 1.0f - 2.0f * __builtin_amdgcn_rcpf(e + 1.0f);
}

__device__ __forceinline__ void async_cp16(const void* g, void* l) {
  __builtin_amdgcn_global_load_lds(
      (const u32 __attribute__((address_space(1)))*)g,
      (u32 __attribute__((address_space(3)))*)l, 16, 0, 0);
}

// ---------------- fused prep (one dispatch) ----------------

#define PREPX_BLKS 2048
#define PREPW_BLKS 1344  // 168 l-tiles x 8 k-tiles

__global__ __launch_bounds__(256) void prep_all(
    const float* __restrict__ x, const float* __restrict__ W,
    const float* __restrict__ M, const float* __restrict__ mu,
    u16* __restrict__ xb, u16* __restrict__ wt, float* __restrict__ xsq,
    float* __restrict__ musq, float* __restrict__ form_sum) {
  __shared__ float lds[64 * 65];  // 16.6 KB; also reused as red[256]
  const int blk = blockIdx.x, tid = threadIdx.x;

  if (blk < PREPX_BLKS) {
    ((uint4*)form_sum)[blk * 256 + tid] = make_uint4(0, 0, 0, 0);
    int wave = tid >> 6, lane = tid & 63;
    int row = blk * 4 + wave;
    const float4* px = (const float4*)(x + (size_t)row * IDIM);
    float4 a = px[lane * 2], b = px[lane * 2 + 1];
    uint4 pk;
    pk.x = (u32)f2bf(a.x) | ((u32)f2bf(a.y) << 16);
    pk.y = (u32)f2bf(a.z) | ((u32)f2bf(a.w) << 16);
    pk.z = (u32)f2bf(b.x) | ((u32)f2bf(b.y) << 16);
    pk.w = (u32)f2bf(b.z) | ((u32)f2bf(b.w) << 16);
    ((uint4*)(xb + (size_t)row * IDIM))[lane] = pk;
    float s = a.x * a.x + a.y * a.y + a.z * a.z + a.w * a.w +
              b.x * b.x + b.y * b.y + b.z * b.z + b.w * b.w;
#pragma unroll
    for (int o = 32; o > 0; o >>= 1) s += __shfl_down(s, o);
    if (lane == 0) xsq[row] = s;
  } else if (blk < PREPX_BLKS + PREPW_BLKS) {
    int b = blk - PREPX_BLKS;
    int l0 = (b % 168) * 64, k0 = (b / 168) * 64;
#pragma unroll
    for (int j = 0; j < 4; ++j) {
      int idx = tid + j * 256;
      int kk = idx >> 4, l4 = idx & 15;
      size_t g = (size_t)(k0 + kk) * NLIT + l0 + l4 * 4;
      float4 w4 = *(const float4*)(W + g);
      float4 m4 = *(const float4*)(M + g);
      lds[kk * 65 + l4 * 4 + 0] = w4.x * m4.x;
      lds[kk * 65 + l4 * 4 + 1] = w4.y * m4.y;
      lds[kk * 65 + l4 * 4 + 2] = w4.z * m4.z;
      lds[kk * 65 + l4 * 4 + 3] = w4.w * m4.w;
    }
    __syncthreads();
    int l = tid >> 2, kq = tid & 3;
    u32 pk[8];
#pragma unroll
    for (int t = 0; t < 8; ++t) {
      u16 lo = f2bf(lds[(kq * 16 + 2 * t) * 65 + l]);
      u16 hi = f2bf(lds[(kq * 16 + 2 * t + 1) * 65 + l]);
      pk[t] = (u32)lo | ((u32)hi << 16);
    }
    u32* dst = (u32*)(wt + (size_t)(l0 + l) * IDIM + k0 + kq * 16);
    ((uint4*)dst)[0] = make_uint4(pk[0], pk[1], pk[2], pk[3]);
    ((uint4*)dst)[1] = make_uint4(pk[4], pk[5], pk[6], pk[7]);
  } else {
    int b = blk - PREPX_BLKS - PREPW_BLKS;
    if (b < 256) {
      float s = 0.f;
#pragma unroll
      for (int j = tid; j < IDIM; j += 256) {
        float v = mu[(size_t)b * IDIM + j];
        wt[(size_t)(NLIT + b) * IDIM + j] = f2bf(v);
        s += v * v;
      }
      float* red = lds;
      red[tid] = s;
      __syncthreads();
      for (int sh = 128; sh > 0; sh >>= 1) {
        if (tid < sh) red[tid] += red[tid + sh];
        __syncthreads();
      }
      if (tid == 0) musq[b] = red[0];
    } else {
      int row = NLIT + 256 + (b - 256);  // 11008..11135
      for (int j = tid; j < IDIM; j += 256) wt[(size_t)row * IDIM + j] = 0;
    }
  }
}

// ---------------- main fused GEMM (double-buffered, 8 waves) ----------------
// Pipeline per K-tile: issue 7 copies for k+1 into other buffer, then
// s_waitcnt vmcnt(7) + s_barrier (prefetch stays in flight), compute,
// s_waitcnt lgkmcnt(0) + s_barrier (reads sampled before buffer release).

__global__ __launch_bounds__(512, 2) void dnnf_gemm(
    const u16* __restrict__ xb, const u16* __restrict__ wt,
    const float* __restrict__ bias, float* __restrict__ form_sum,
    float* __restrict__ dotbuf) {
  __shared__ __align__(16) char smraw[2 * BUFB];  // 114688 B -> 1 block/CU
  float* slit = (float*)smraw;                    // epilogue view 128 x SLITP

  const int tid = threadIdx.x;
  const int wave = tid >> 6, lane = tid & 63;
  const int wm = wave & 3, wn = wave >> 2;  // wave tile: 64 rows x 96 cols
  // grid: x = m (32, multiple of 8 -> XCD-pinned m-tiles), y = n (58)
  const int m0 = blockIdx.x * BM, n0 = blockIdx.y * BN;
  const int q = lane >> 4, cn = lane & 15;

  // staging: chunk c = tid + i*512, r = c>>3, kg = (c&7) ^ (r&7)
  const int kg8 = ((tid & 7) ^ ((tid >> 3) & 7)) * 8;
  const u16* pa = xb + (size_t)(m0 + (tid >> 3)) * IDIM + kg8;
  const u16* pb = wt + (size_t)(n0 + (tid >> 3)) * IDIM + kg8;
  const int dA = tid * 16;           // + i*8192, i<4
  const int dB = ABYTES + tid * 16;  // + i*8192, i<3

  const int kg0_16 = ((q ^ (cn & 7)) << 4);
  int offA[4], offB[6];
#pragma unroll
  for (int mf = 0; mf < 4; ++mf)
    offA[mf] = (wm * 64 + mf * 16 + cn) * 128 + kg0_16;
#pragma unroll
  for (int nf = 0; nf < 6; ++nf)
    offB[nf] = ABYTES + (wn * 96 + nf * 16 + cn) * 128 + kg0_16;

  f32x4 acc[4][6];
#pragma unroll
  for (int a = 0; a < 4; ++a)
#pragma unroll
    for (int b = 0; b < 6; ++b) acc[a][b] = (f32x4){0.f, 0.f, 0.f, 0.f};

  // prologue: tile 0 -> buffer 0
#pragma unroll
  for (int i = 0; i < 4; ++i)
    async_cp16(pa + (size_t)i * 64 * IDIM, smraw + dA + i * 8192);
#pragma unroll
  for (int i = 0; i < 3; ++i)
    async_cp16(pb + (size_t)i * 64 * IDIM, smraw + dB + i * 8192);
  pa += BK;
  pb += BK;

#pragma unroll
  for (int kt = 0; kt < 8; ++kt) {
    const char* bufc = smraw + (kt & 1) * BUFB;
    if (kt < 7) {
      char* bufn = smraw + ((kt + 1) & 1) * BUFB;
#pragma unroll
      for (int i = 0; i < 4; ++i)
        async_cp16(pa + (size_t)i * 64 * IDIM, bufn + dA + i * 8192);
#pragma unroll
      for (int i = 0; i < 3; ++i)
        async_cp16(pb + (size_t)i * 64 * IDIM, bufn + dB + i * 8192);
      pa += BK;
      pb += BK;
      asm volatile("s_waitcnt vmcnt(7)\n\ts_barrier" ::: "memory");
    } else {
      asm volatile("s_waitcnt vmcnt(0)\n\ts_barrier" ::: "memory");
    }
#pragma unroll
    for (int ks = 0; ks < 2; ++ks) {
      const int x64 = ks ? 64 : 0;
      bf16x8 af[4], bfr[6];
#pragma unroll
      for (int mf = 0; mf < 4; ++mf)
        af[mf] = *(const bf16x8*)(bufc + (offA[mf] ^ x64));
#pragma unroll
      for (int nf = 0; nf < 6; ++nf)
        bfr[nf] = *(const bf16x8*)(bufc + (offB[nf] ^ x64));
#pragma unroll
      for (int mf = 0; mf < 4; ++mf)
#pragma unroll
        for (int nf = 0; nf < 6; ++nf)
          acc[mf][nf] = __builtin_amdgcn_mfma_f32_16x16x32_bf16(
              af[mf], bfr[nf], acc[mf][nf], 0, 0, 0);
    }
    if (kt < 7)
      asm volatile("s_waitcnt lgkmcnt(0)\n\ts_barrier" ::: "memory");
  }
  __syncthreads();  // full drain before LDS reuse as slit

  if (n0 < NLIT) {
    float bv[6];
#pragma unroll
    for (int nf = 0; nf < 6; ++nf) bv[nf] = bias[n0 + wn * 96 + nf * 16 + cn];

    // two phases of 128 rows, one 128 x SLITP slit tile (100 KB < 112 KB)
#pragma unroll
    for (int ph = 0; ph < 2; ++ph) {
      if (ph) __syncthreads();  // phase-0 reads done before overwrite
      if ((wm >> 1) == ph) {
#pragma unroll
        for (int nf = 0; nf < 6; ++nf) {
          int col = wn * 96 + nf * 16 + cn;
#pragma unroll
          for (int mf = 0; mf < 4; ++mf)
#pragma unroll
            for (int reg = 0; reg < 4; ++reg) {
              int lr = (wm & 1) * 64 + mf * 16 + q * 4 + reg;
              slit[lr * SLITP + col] = fast_tanh(acc[mf][nf][reg] + bv[nf]);
            }
        }
      }
      __syncthreads();

      int r = tid >> 2, sub = tid & 3;  // 128 rows x 4 threads (48 lits each)
      const float* lrow = slit + r * SLITP + sub * 48;
      int c0 = ((n0 + sub * 48) / 12) * 3;
      size_t grow = (size_t)(m0 + ph * 128 + r) * NFORM;
      float run = 0.f;
      int fprev = -1;
#pragma unroll
      for (int tr = 0; tr < 4; ++tr) {
        const float* p = lrow + tr * 12;
        float s2 = p[0] + p[1];
        float s4 = p[2] + p[3] + p[4] + p[5];
        float s6 = p[6] + p[7] + p[8] + p[9] + p[10] + p[11];
        float v = fast_tanh(s2 - 0.5f) + fast_tanh(s4 - 2.5f) +
                  fast_tanh(s6 - 4.5f);
        int c = c0 + tr * 3;
        int f = (c < 384)    ? (c / 6)
                : (c < 960)  ? 64 + (c - 384) / 9
                : (c < 1728) ? 128 + (c - 960) / 12
                             : 192 + (c - 1728) / 15;
        if (f != fprev) {
          if (fprev >= 0) atomicAdd(form_sum + grow + fprev, run);
          fprev = f;
          run = 0.f;
        }
        run += v;
      }
      atomicAdd(form_sum + grow + fprev, run);
    }
  } else {
    // mu tiles: store raw x.mu dots
#pragma unroll
    for (int nf = 0; nf < 6; ++nf) {
      int col = n0 - NLIT + wn * 96 + nf * 16 + cn;
      if (col < NFORM) {
#pragma unroll
        for (int mf = 0; mf < 4; ++mf)
#pragma unroll
          for (int reg = 0; reg < 4; ++reg) {
            int row = wm * 64 + mf * 16 + q * 4 + reg;
            dotbuf[(size_t)(m0 + row) * NFORM + col] = acc[mf][nf][reg];
          }
      }
    }
  }
}

// ---------------- finale: RBF softmax * dnnf (wave-per-row) ----------------

__global__ __launch_bounds__(256) void finale(
    const float* __restrict__ form_sum, const float* __restrict__ dotbuf,
    const float* __restrict__ xsq, const float* __restrict__ musq,
    const float* __restrict__ sigma, float* __restrict__ out) {
  int wave = threadIdx.x >> 6, lane = threadIdx.x & 63;
  int r = blockIdx.x * 4 + wave;
  size_t base = (size_t)r * NFORM;
  float xs = xsq[r];
  float e[4], s = 0.f;
#pragma unroll
  for (int j = 0; j < 4; ++j) {
    int f = j * 64 + lane;
    float sq = xs - 2.0f * dotbuf[base + f] + musq[f];
    float sg = sigma[f];
    float p = __expf(-0.5f * sq / (sg * sg));
    e[j] = __expf(2.0f * p);  // TEMPERATURE=2; values in [1, e^2]
    s += e[j];
  }
#pragma unroll
  for (int o = 32; o > 0; o >>= 1) s += __shfl_xor(s, o);
  float inv = __builtin_amdgcn_rcpf(s);
#pragma unroll
  for (int j = 0; j < 4; ++j) {
    int f = j * 64 + lane;
    float dn = fast_tanh(form_sum[base + f] + (float)(6 + 3 * j) - 1.5f);
    out[base + f] = dn * e[j] * inv;
  }
}

// ---------------- launch ----------------

extern "C" void kernel_launch(void* const* d_in, const int* in_sizes, int n_in,
                              void* d_out, int out_size, void* d_ws,
                              size_t ws_size, hipStream_t stream) {
  const float* x = (const float*)d_in[0];
  const float* W = (const float*)d_in[1];
  const float* M = (const float*)d_in[2];
  const float* bias = (const float*)d_in[3];
  const float* mu = (const float*)d_in[4];
  const float* sigma = (const float*)d_in[5];
  float* out = (float*)d_out;

  float* form_sum = (float*)d_ws;                       // 8 MB
  float* dotbuf = form_sum + (size_t)BATCH * NFORM;     // 8 MB
  u16* xb = (u16*)(dotbuf + (size_t)BATCH * NFORM);     // 8 MB
  u16* wt = xb + (size_t)BATCH * IDIM;                  // 11.4 MB
  float* xsq = (float*)(wt + (size_t)WT_ROWS * IDIM);   // 32 KB
  float* musq = xsq + BATCH;                            // 1 KB

  prep_all<<<PREPX_BLKS + PREPW_BLKS + 384, 256, 0, stream>>>(
      x, W, M, mu, xb, wt, xsq, musq, form_sum);
  // grid: x = m (32, multiple of 8 -> XCD-pinned m-tiles), y = n (58)
  dnnf_gemm<<<dim3(BATCH / BM, WT_ROWS / BN), 512, 0, stream>>>(xb, wt, bias,
                                                                form_sum, dotbuf);
  finale<<<BATCH / 4, 256, 0, stream>>>(form_sum, dotbuf, xsq, musq, sigma, out);
}

// Round 2
// 237.475 us; speedup vs baseline: 1.1378x; 1.1378x over previous
//
#include <hip/hip_runtime.h>

// DNNF fused pipeline for MI355X (gfx950). R7 = R5 revert + BK 64->32:
// LDS buffer 40960->20480 B (dbuf 40960) -> 4 blocks/CU by LDS; VGPR caps
// occupancy at 3 waves/SIMD (launch_bounds 256,3) -> 12 waves/CU vs R5's 8.
// R6 lesson: 1 block/CU lockstep regressed (177us); concurrency, not cache
// traffic, is the binding constraint. Epilogue re-phased to 4x32 rows so the
// slit tile (25 KB) fits the smaller LDS; slit reads vectorized to float4.

#define BATCH 8192
#define IDIM 512
#define NFORM 256
#define NLIT 10752
#define WT_ROWS 11136  // NLIT + 256 mu + 128 zero pad; /192 = 58 tiles

#define BM 128
#define BN 192
#define BK 32
#define ABYTES 8192    // 128*32*2
#define BUFB 20480     // one LDS buffer: A 8192 + B 12288
#define SLITP 196      // slit row stride (floats)

typedef __bf16 bf16x8 __attribute__((ext_vector_type(8)));
typedef float f32x4 __attribute__((ext_vector_type(4)));
typedef unsigned short u16;
typedef unsigned int u32;

__device__ __forceinline__ u16 f2bf(float f) {
  u32 u = __float_as_uint(f);
  u = (u + 0x7fffu + ((u >> 16) & 1u)) >> 16;  // RNE
  return (u16)u;
}

__device__ __forceinline__ float fast_tanh(float x) {
  float e = __expf(2.0f * x);
  return 1.0f - 2.0f * __builtin_amdgcn_rcpf(e + 1.0f);
}

__device__ __forceinline__ void async_cp16(const void* g, void* l) {
  __builtin_amdgcn_global_load_lds(
      (const u32 __attribute__((address_space(1)))*)g,
      (u32 __attribute__((address_space(3)))*)l, 16, 0, 0);
}

// ---------------- fused prep (one dispatch) ----------------

#define PREPX_BLKS 2048
#define PREPW_BLKS 1344  // 168 l-tiles x 8 k-tiles

__global__ __launch_bounds__(256) void prep_all(
    const float* __restrict__ x, const float* __restrict__ W,
    const float* __restrict__ M, const float* __restrict__ mu,
    u16* __restrict__ xb, u16* __restrict__ wt, float* __restrict__ xsq,
    float* __restrict__ musq, float* __restrict__ form_sum) {
  __shared__ float lds[64 * 65];  // 16.6 KB; also reused as red[256]
  const int blk = blockIdx.x, tid = threadIdx.x;

  if (blk < PREPX_BLKS) {
    ((uint4*)form_sum)[blk * 256 + tid] = make_uint4(0, 0, 0, 0);
    int wave = tid >> 6, lane = tid & 63;
    int row = blk * 4 + wave;
    const float4* px = (const float4*)(x + (size_t)row * IDIM);
    float4 a = px[lane * 2], b = px[lane * 2 + 1];
    uint4 pk;
    pk.x = (u32)f2bf(a.x) | ((u32)f2bf(a.y) << 16);
    pk.y = (u32)f2bf(a.z) | ((u32)f2bf(a.w) << 16);
    pk.z = (u32)f2bf(b.x) | ((u32)f2bf(b.y) << 16);
    pk.w = (u32)f2bf(b.z) | ((u32)f2bf(b.w) << 16);
    ((uint4*)(xb + (size_t)row * IDIM))[lane] = pk;
    float s = a.x * a.x + a.y * a.y + a.z * a.z + a.w * a.w +
              b.x * b.x + b.y * b.y + b.z * b.z + b.w * b.w;
#pragma unroll
    for (int o = 32; o > 0; o >>= 1) s += __shfl_down(s, o);
    if (lane == 0) xsq[row] = s;
  } else if (blk < PREPX_BLKS + PREPW_BLKS) {
    int b = blk - PREPX_BLKS;
    int l0 = (b % 168) * 64, k0 = (b / 168) * 64;
#pragma unroll
    for (int j = 0; j < 4; ++j) {
      int idx = tid + j * 256;
      int kk = idx >> 4, l4 = idx & 15;
      size_t g = (size_t)(k0 + kk) * NLIT + l0 + l4 * 4;
      float4 w4 = *(const float4*)(W + g);
      float4 m4 = *(const float4*)(M + g);
      lds[kk * 65 + l4 * 4 + 0] = w4.x * m4.x;
      lds[kk * 65 + l4 * 4 + 1] = w4.y * m4.y;
      lds[kk * 65 + l4 * 4 + 2] = w4.z * m4.z;
      lds[kk * 65 + l4 * 4 + 3] = w4.w * m4.w;
    }
    __syncthreads();
    int l = tid >> 2, kq = tid & 3;
    u32 pk[8];
#pragma unroll
    for (int t = 0; t < 8; ++t) {
      u16 lo = f2bf(lds[(kq * 16 + 2 * t) * 65 + l]);
      u16 hi = f2bf(lds[(kq * 16 + 2 * t + 1) * 65 + l]);
      pk[t] = (u32)lo | ((u32)hi << 16);
    }
    u32* dst = (u32*)(wt + (size_t)(l0 + l) * IDIM + k0 + kq * 16);
    ((uint4*)dst)[0] = make_uint4(pk[0], pk[1], pk[2], pk[3]);
    ((uint4*)dst)[1] = make_uint4(pk[4], pk[5], pk[6], pk[7]);
  } else {
    int b = blk - PREPX_BLKS - PREPW_BLKS;
    if (b < 256) {
      float s = 0.f;
#pragma unroll
      for (int j = tid; j < IDIM; j += 256) {
        float v = mu[(size_t)b * IDIM + j];
        wt[(size_t)(NLIT + b) * IDIM + j] = f2bf(v);
        s += v * v;
      }
      float* red = lds;
      red[tid] = s;
      __syncthreads();
      for (int sh = 128; sh > 0; sh >>= 1) {
        if (tid < sh) red[tid] += red[tid + sh];
        __syncthreads();
      }
      if (tid == 0) musq[b] = red[0];
    } else {
      int row = NLIT + 256 + (b - 256);  // 11008..11135
      for (int j = tid; j < IDIM; j += 256) wt[(size_t)row * IDIM + j] = 0;
    }
  }
}

// ---------------- main fused GEMM (double-buffered, BK=32) ----------------
// Per K-tile: issue 5 copies for k+1 into other buffer, s_waitcnt vmcnt(5)
// + s_barrier (prefetch stays in flight), 24 MFMA, lgkmcnt(0) + s_barrier.
// 16 tiles; stalls overlap across ~3 resident blocks per CU.

__global__ __launch_bounds__(256, 3) void dnnf_gemm(
    const u16* __restrict__ xb, const u16* __restrict__ wt,
    const float* __restrict__ bias, float* __restrict__ form_sum,
    float* __restrict__ dotbuf) {
  __shared__ __align__(16) char smraw[2 * BUFB];  // 40960 B -> 4 blocks by LDS
  float* slit = (float*)smraw;                    // epilogue view 32 x SLITP

  const int tid = threadIdx.x;
  const int wave = tid >> 6, lane = tid & 63;
  const int wm = wave & 1, wn = wave >> 1;  // wave tile: 64 rows x 96 cols
  // grid: x = m (64, multiple of 8 -> XCD-pinned m-tiles), y = n (58)
  const int m0 = blockIdx.x * BM, n0 = blockIdx.y * BN;
  const int q = lane >> 4, cn = lane & 15;

  // staging: 16B chunk c = tid + i*256, row r = c>>2, kgroup (c&3)^s(r),
  // s(r) = (r&3)^((r>>2)&3). Since 64|i-stride, s depends only on tid.
  const int kgs = ((tid & 3) ^ ((tid >> 2) & 3) ^ ((tid >> 4) & 3)) * 8;
  const u16* pa = xb + (size_t)(m0 + (tid >> 2)) * IDIM + kgs;
  const u16* pb = wt + (size_t)(n0 + (tid >> 2)) * IDIM + kgs;
  const int dA = tid * 16;           // + i*4096, i<2
  const int dB = ABYTES + tid * 16;  // + i*4096, i<3

  // fragment read: row R (R&3 == cn&3, (R>>2)&3 == (cn>>2)&3), kgroup q
  const int swz16 = (q ^ (cn & 3) ^ ((cn >> 2) & 3)) << 4;
  int offA[4], offB[6];
#pragma unroll
  for (int mf = 0; mf < 4; ++mf)
    offA[mf] = (wm * 64 + mf * 16 + cn) * 64 + swz16;
#pragma unroll
  for (int nf = 0; nf < 6; ++nf)
    offB[nf] = ABYTES + (wn * 96 + nf * 16 + cn) * 64 + swz16;

  f32x4 acc[4][6];
#pragma unroll
  for (int a = 0; a < 4; ++a)
#pragma unroll
    for (int b = 0; b < 6; ++b) acc[a][b] = (f32x4){0.f, 0.f, 0.f, 0.f};

  // prologue: tile 0 -> buffer 0
#pragma unroll
  for (int i = 0; i < 2; ++i)
    async_cp16(pa + (size_t)i * 64 * IDIM, smraw + dA + i * 4096);
#pragma unroll
  for (int i = 0; i < 3; ++i)
    async_cp16(pb + (size_t)i * 64 * IDIM, smraw + dB + i * 4096);
  pa += BK;
  pb += BK;

#pragma unroll
  for (int kt = 0; kt < 16; ++kt) {
    const char* bufc = smraw + (kt & 1) * BUFB;
    if (kt < 15) {
      char* bufn = smraw + ((kt + 1) & 1) * BUFB;
#pragma unroll
      for (int i = 0; i < 2; ++i)
        async_cp16(pa + (size_t)i * 64 * IDIM, bufn + dA + i * 4096);
#pragma unroll
      for (int i = 0; i < 3; ++i)
        async_cp16(pb + (size_t)i * 64 * IDIM, bufn + dB + i * 4096);
      pa += BK;
      pb += BK;
      asm volatile("s_waitcnt vmcnt(5)\n\ts_barrier" ::: "memory");
    } else {
      asm volatile("s_waitcnt vmcnt(0)\n\ts_barrier" ::: "memory");
    }
    bf16x8 af[4], bfr[6];
#pragma unroll
    for (int mf = 0; mf < 4; ++mf)
      af[mf] = *(const bf16x8*)(bufc + offA[mf]);
#pragma unroll
    for (int nf = 0; nf < 6; ++nf)
      bfr[nf] = *(const bf16x8*)(bufc + offB[nf]);
#pragma unroll
    for (int mf = 0; mf < 4; ++mf)
#pragma unroll
      for (int nf = 0; nf < 6; ++nf)
        acc[mf][nf] = __builtin_amdgcn_mfma_f32_16x16x32_bf16(
            af[mf], bfr[nf], acc[mf][nf], 0, 0, 0);
    if (kt < 15)
      asm volatile("s_waitcnt lgkmcnt(0)\n\ts_barrier" ::: "memory");
  }
  __syncthreads();  // full drain before LDS reuse as slit

  if (n0 < NLIT) {
    float bv[6];
#pragma unroll
    for (int nf = 0; nf < 6; ++nf) bv[nf] = bias[n0 + wn * 96 + nf * 16 + cn];

    // four phases of 32 rows; slit tile 32 x SLITP (25 KB <= 40 KB)
#pragma unroll
    for (int ph = 0; ph < 4; ++ph) {
      if (ph) __syncthreads();  // prev-phase reads done before overwrite
      if (wm == (ph >> 1)) {
#pragma unroll
        for (int mh = 0; mh < 2; ++mh) {
          int mf = 2 * (ph & 1) + mh;
#pragma unroll
          for (int nf = 0; nf < 6; ++nf) {
            int col = wn * 96 + nf * 16 + cn;
#pragma unroll
            for (int reg = 0; reg < 4; ++reg) {
              int sr = mh * 16 + q * 4 + reg;
              slit[sr * SLITP + col] = fast_tanh(acc[mf][nf][reg] + bv[nf]);
            }
          }
        }
      }
      __syncthreads();

      int r = tid >> 3, sub = tid & 7;  // 32 rows x 8 threads (24 lits each)
      const float* lrow = slit + r * SLITP + sub * 24;
      int c0 = ((n0 + sub * 24) / 12) * 3;
      size_t grow = (size_t)(m0 + ph * 32 + r) * NFORM;
      float run = 0.f;
      int fprev = -1;
#pragma unroll
      for (int tr = 0; tr < 2; ++tr) {
        const float4 a0 = *(const float4*)(lrow + tr * 12);
        const float4 a1 = *(const float4*)(lrow + tr * 12 + 4);
        const float4 a2 = *(const float4*)(lrow + tr * 12 + 8);
        float s2 = a0.x + a0.y;
        float s4 = a0.z + a0.w + a1.x + a1.y;
        float s6 = a1.z + a1.w + a2.x + a2.y + a2.z + a2.w;
        float v = fast_tanh(s2 - 0.5f) + fast_tanh(s4 - 2.5f) +
                  fast_tanh(s6 - 4.5f);
        int c = c0 + tr * 3;
        int f = (c < 384)    ? (c / 6)
                : (c < 960)  ? 64 + (c - 384) / 9
                : (c < 1728) ? 128 + (c - 960) / 12
                             : 192 + (c - 1728) / 15;
        if (f != fprev) {
          if (fprev >= 0) atomicAdd(form_sum + grow + fprev, run);
          fprev = f;
          run = 0.f;
        }
        run += v;
      }
      atomicAdd(form_sum + grow + fprev, run);
    }
  } else {
    // mu tiles: store raw x.mu dots
#pragma unroll
    for (int nf = 0; nf < 6; ++nf) {
      int col = n0 - NLIT + wn * 96 + nf * 16 + cn;
      if (col < NFORM) {
#pragma unroll
        for (int mf = 0; mf < 4; ++mf)
#pragma unroll
          for (int reg = 0; reg < 4; ++reg) {
            int row = wm * 64 + mf * 16 + q * 4 + reg;
            dotbuf[(size_t)(m0 + row) * NFORM + col] = acc[mf][nf][reg];
          }
      }
    }
  }
}

// ---------------- finale: RBF softmax * dnnf (wave-per-row) ----------------

__global__ __launch_bounds__(256) void finale(
    const float* __restrict__ form_sum, const float* __restrict__ dotbuf,
    const float* __restrict__ xsq, const float* __restrict__ musq,
    const float* __restrict__ sigma, float* __restrict__ out) {
  int wave = threadIdx.x >> 6, lane = threadIdx.x & 63;
  int r = blockIdx.x * 4 + wave;
  size_t base = (size_t)r * NFORM;
  float xs = xsq[r];
  float e[4], s = 0.f;
#pragma unroll
  for (int j = 0; j < 4; ++j) {
    int f = j * 64 + lane;
    float sq = xs - 2.0f * dotbuf[base + f] + musq[f];
    float sg = sigma[f];
    float p = __expf(-0.5f * sq / (sg * sg));
    e[j] = __expf(2.0f * p);  // TEMPERATURE=2; values in [1, e^2]
    s += e[j];
  }
#pragma unroll
  for (int o = 32; o > 0; o >>= 1) s += __shfl_xor(s, o);
  float inv = __builtin_amdgcn_rcpf(s);
#pragma unroll
  for (int j = 0; j < 4; ++j) {
    int f = j * 64 + lane;
    float dn = fast_tanh(form_sum[base + f] + (float)(6 + 3 * j) - 1.5f);
    out[base + f] = dn * e[j] * inv;
  }
}

// ---------------- launch ----------------

extern "C" void kernel_launch(void* const* d_in, const int* in_sizes, int n_in,
                              void* d_out, int out_size, void* d_ws,
                              size_t ws_size, hipStream_t stream) {
  const float* x = (const float*)d_in[0];
  const float* W = (const float*)d_in[1];
  const float* M = (const float*)d_in[2];
  const float* bias = (const float*)d_in[3];
  const float* mu = (const float*)d_in[4];
  const float* sigma = (const float*)d_in[5];
  float* out = (float*)d_out;

  float* form_sum = (float*)d_ws;                       // 8 MB
  float* dotbuf = form_sum + (size_t)BATCH * NFORM;     // 8 MB
  u16* xb = (u16*)(dotbuf + (size_t)BATCH * NFORM);     // 8 MB
  u16* wt = xb + (size_t)BATCH * IDIM;                  // 11.4 MB
  float* xsq = (float*)(wt + (size_t)WT_ROWS * IDIM);   // 32 KB
  float* musq = xsq + BATCH;                            // 1 KB

  prep_all<<<PREPX_BLKS + PREPW_BLKS + 384, 256, 0, stream>>>(
      x, W, M, mu, xb, wt, xsq, musq, form_sum);
  // grid: x = m (64, multiple of 8 -> XCD-pinned m-tiles), y = n (58)
  dnnf_gemm<<<dim3(BATCH / BM, WT_ROWS / BN), 256, 0, stream>>>(xb, wt, bias,
                                                                form_sum, dotbuf);
  finale<<<BATCH / 4, 256, 0, stream>>>(form_sum, dotbuf, xsq, musq, sigma, out);
}